// Round 3
// baseline (324.553 us; speedup 1.0000x reference)
//
#include <hip/hip_runtime.h>
#include <hip/hip_bf16.h>

// Problem: B=8, S=4096, D=768
//   y = tanh(x @ W); scores = y . v; w = softmax_S(scores); out = sum_s w * x
constexpr int Bb = 8;
constexpr int Ss = 4096;
constexpr int Dd = 768;
constexpr int Mm = Bb * Ss;      // 32768 rows

typedef __bf16 bf16x8 __attribute__((ext_vector_type(8)));
typedef float f32x4 __attribute__((ext_vector_type(4)));

__device__ __forceinline__ float fast_tanh(float x) {
    return 1.f - 2.f / (__expf(2.f * x) + 1.f);
}

__device__ __forceinline__ void load_lds16(const void* g, void* l) {
    __builtin_amdgcn_global_load_lds(
        (const __attribute__((address_space(1))) unsigned int*)g,
        (__attribute__((address_space(3))) unsigned int*)l, 16, 0, 0);
}

// ---------------- Kernel 0: W[k][n] fp32 -> Wt[n][k] bf16, with the LDS
// bank-swizzle PRE-BAKED into the global layout: within each 64B k-chunk of
// row n, 16B slot s holds original slot s ^ ((n>>1)&3). global_load_lds then
// writes LDS linearly and the GEMM reads with the same XOR -> 2-way max
// bank aliasing (free).
__global__ __launch_bounds__(256) void convW(const float* __restrict__ W,
                                             __bf16* __restrict__ Wt) {
    __shared__ float tile[32][33];
    const int tx = threadIdx.x & 31;
    const int ty = threadIdx.x >> 5;
    const int kb = blockIdx.x * 32;
    const int nb = blockIdx.y * 32;
#pragma unroll
    for (int i = 0; i < 32; i += 8)
        tile[ty + i][tx] = W[(size_t)(kb + ty + i) * Dd + nb + tx];
    __syncthreads();
#pragma unroll
    for (int i = 0; i < 32; i += 8) {
        const int n = nb + ty + i;
        const int txs = (tx & 7) | ((((tx >> 3) & 3) ^ ((n >> 1) & 3)) << 3);
        Wt[(size_t)n * Dd + kb + txs] = (__bf16)tile[tx][ty + i];
    }
}

// ---------------- Kernel 1: scores2[nb][m] = sum_n v[n]*tanh( (x@W)[m][n] )
// BM=64 x BN=384, n-split 2. 512 thr = 8 waves (2wm x 4wn), wave tile 32x96,
// 12 MFMA + 6 ds_read_b128 per K-step. A is DIRECT global->reg (the 16x16x32
// A-frag is lane lid reading 8 consecutive k at quad*8 -> two float4 loads
// from x; no LDS round-trip, no ds_write, A latency hidden by 1-step reg
// prefetch that flies across barriers). B: gl_lds from pre-swizzled Wt into
// 3-deep Bs (2-step flight). Manual counted vmcnt at each barrier: 7 younger
// VMEM ops in flight (4 A-pref + 3 gl_lds) while publishing a buffer; never
// drains to 0 in the loop. T5 setprio around MFMAs. LDS = 72 KB + 1 KB ->
// 2 blocks/CU; grid 1024 = exactly 2 full residency rounds (no tail).
// XCD-bijective swizzle: the 2 nb-blocks of one mb land on the same XCD.
__global__ __launch_bounds__(512, 4) void scores_gemm(
    const float* __restrict__ x, const __bf16* __restrict__ Wt,
    const float* __restrict__ v, float* __restrict__ scores2) {
    __shared__ __bf16 Bs[3][384 * 32];    // 3 x 24 KB
    __shared__ float ssc[8][32];

    const int t = threadIdx.x;
    // XCD swizzle: 1024 blocks, 8 XCDs -> XCD x owns ids [x*128,(x+1)*128)
    const int id = blockIdx.x;
    const int ids = ((id & 7) * 128) + (id >> 3);
    const int mb = ids >> 1;              // 0..511
    const int nb = ids & 1;               // 0..1
    const int lane = t & 63;
    const int wave = t >> 6;
    const int wm = wave >> 2;             // 0..1 (32-row half)
    const int wn = wave & 3;              // 0..3 (96-col slice)
    const int quad = lane >> 4;
    const int lid = lane & 15;
    const int rslot = ((quad ^ ((lid >> 1) & 3)) * 8);   // B-read swizzle

    // A direct: rows mb*64 + wm*32 + tm*16 + lid; k-offset k*32 + quad*8
    const float* ag0 = x + (size_t)(mb * 64 + wm * 32 + lid) * Dd + quad * 8;
    const float* ag1 = ag0 + (size_t)16 * Dd;

    // B staging: 3 x 16B per thread, flat j*8192 + t*16 bytes over [384 x 64B]
    const __bf16* bg[3];
    int bl[3];
#pragma unroll
    for (int j = 0; j < 3; ++j) {
        const int flat = j * 8192 + t * 16;   // bytes
        const int col = flat >> 6;
        bg[j] = Wt + (size_t)(nb * 384 + col) * Dd + ((flat & 63) >> 1);
        bl[j] = flat >> 1;                    // bf16 index into Bs[buf]
    }

    f32x4 acc[2][6];
#pragma unroll
    for (int tm = 0; tm < 2; ++tm)
#pragma unroll
        for (int nt = 0; nt < 6; ++nt) acc[tm][nt] = (f32x4){0.f, 0.f, 0.f, 0.f};

    // ---- prologue: G(0); A-pref(0); G(1)  [order makes top-of-step vmcnt(7)
    // retire exactly G(0)]
    float4 ap0a, ap0b, ap1a, ap1b;
#pragma unroll
    for (int j = 0; j < 3; ++j) load_lds16(bg[j], &Bs[0][bl[j]]);
    ap0a = *(const float4*)(ag0);
    ap0b = *(const float4*)(ag0 + 4);
    ap1a = *(const float4*)(ag1);
    ap1b = *(const float4*)(ag1 + 4);
#pragma unroll
    for (int j = 0; j < 3; ++j) load_lds16(bg[j] + 32, &Bs[1][bl[j]]);

#pragma unroll
    for (int k = 0; k < 24; ++k) {
        // publish buf k: all VMEM older than the 7 (4 A-pref + 3 gl_lds)
        // issued last step must be retired -> G(k) done. Tail: at k=23 only
        // 4 A-pref are younger than G(23).
        if (k == 23) asm volatile("s_waitcnt vmcnt(4)" ::: "memory");
        else         asm volatile("s_waitcnt vmcnt(7)" ::: "memory");
        __builtin_amdgcn_sched_barrier(0);
        __builtin_amdgcn_s_barrier();
        __builtin_amdgcn_sched_barrier(0);

        // consume A(k): compiler inserts a counted vmcnt here (gl_lds issued
        // after the A-pref loads stay in flight)
        bf16x8 af0, af1;
        af0[0] = (__bf16)ap0a.x; af0[1] = (__bf16)ap0a.y;
        af0[2] = (__bf16)ap0a.z; af0[3] = (__bf16)ap0a.w;
        af0[4] = (__bf16)ap0b.x; af0[5] = (__bf16)ap0b.y;
        af0[6] = (__bf16)ap0b.z; af0[7] = (__bf16)ap0b.w;
        af1[0] = (__bf16)ap1a.x; af1[1] = (__bf16)ap1a.y;
        af1[2] = (__bf16)ap1a.z; af1[3] = (__bf16)ap1a.w;
        af1[4] = (__bf16)ap1b.x; af1[5] = (__bf16)ap1b.y;
        af1[6] = (__bf16)ap1b.z; af1[7] = (__bf16)ap1b.w;

        if (k < 23) {                     // A prefetch for step k+1 (regs)
            ap0a = *(const float4*)(ag0 + (k + 1) * 32);
            ap0b = *(const float4*)(ag0 + (k + 1) * 32 + 4);
            ap1a = *(const float4*)(ag1 + (k + 1) * 32);
            ap1b = *(const float4*)(ag1 + (k + 1) * 32 + 4);
        }
        if (k < 22) {                     // B for buf k+2 (gl_lds, 2-step flight)
#pragma unroll
            for (int j = 0; j < 3; ++j)
                load_lds16(bg[j] + (k + 2) * 32, &Bs[(k + 2) % 3][bl[j]]);
        }
        __builtin_amdgcn_sched_barrier(0);

        const __bf16* bsp = &Bs[k % 3][(wn * 96 + lid) * 32 + rslot];
        __builtin_amdgcn_s_setprio(1);
#pragma unroll
        for (int nt = 0; nt < 6; ++nt) {
            const bf16x8 bfr = *(const bf16x8*)(bsp + nt * 512);
            acc[0][nt] = __builtin_amdgcn_mfma_f32_16x16x32_bf16(af0, bfr, acc[0][nt], 0, 0, 0);
            acc[1][nt] = __builtin_amdgcn_mfma_f32_16x16x32_bf16(af1, bfr, acc[1][nt], 0, 0, 0);
        }
        __builtin_amdgcn_s_setprio(0);
    }

    // ---- epilogue: fold tanh*v over this block's 384 cols, reduce to rows
    float vv[6];
#pragma unroll
    for (int nt = 0; nt < 6; ++nt)
        vv[nt] = v[nb * 384 + wn * 96 + nt * 16 + lid];

#pragma unroll
    for (int tm = 0; tm < 2; ++tm)
#pragma unroll
        for (int r = 0; r < 4; ++r) {
            float s = 0.f;
#pragma unroll
            for (int nt = 0; nt < 6; ++nt) s += vv[nt] * fast_tanh(acc[tm][nt][r]);
            // C layout: col=lid, row=quad*4+r
            s += __shfl_xor(s, 1);
            s += __shfl_xor(s, 2);
            s += __shfl_xor(s, 4);
            s += __shfl_xor(s, 8);
            if (lid == 0) ssc[wave][tm * 16 + quad * 4 + r] = s;
        }
    __syncthreads();
    if (t < 64) {
        const int wmh = t >> 5;           // which 32-row half
        const int rl = t & 31;
        float s = 0.f;
#pragma unroll
        for (int ww = 0; ww < 4; ++ww) s += ssc[wmh * 4 + ww][rl];
        scores2[(size_t)nb * Mm + mb * 64 + t] = s;   // no atomics, no memset
    }
}

// ---------------- Kernel 2: softmax over S per batch row.
// Reads 2 n-split partials, writes UNNORMALIZED e to weights, 1/sum to sinv.
__global__ __launch_bounds__(256) void softmax_k(const float* __restrict__ scores2,
                                                 float* __restrict__ weights,
                                                 float* __restrict__ sinv) {
    const int b = blockIdx.x;
    const int t = threadIdx.x;
    const float* s0 = scores2 + (size_t)b * Ss;
    const float* s1 = s0 + Mm;
    float* wgt = weights + (size_t)b * Ss;
    __shared__ float red[256];

    float mx = -1e30f;
    for (int i = t; i < Ss; i += 256) {
        const float sc = s0[i] + s1[i];
        wgt[i] = sc;                      // stash summed score
        mx = fmaxf(mx, sc);
    }
    red[t] = mx;
    __syncthreads();
    for (int o = 128; o > 0; o >>= 1) {
        if (t < o) red[t] = fmaxf(red[t], red[t + o]);
        __syncthreads();
    }
    mx = red[0];
    __syncthreads();
    float sum = 0.f;
    for (int i = t; i < Ss; i += 256) {
        const float e = __expf(wgt[i] - mx);
        wgt[i] = e;                       // unnormalized weight
        sum += e;
    }
    red[t] = sum;
    __syncthreads();
    for (int o = 128; o > 0; o >>= 1) {
        if (t < o) red[t] += red[t + o];
        __syncthreads();
    }
    if (t == 0) sinv[b] = 1.f / red[0];
}

// ---------------- Kernel 3a: per-chunk partial pool (no atomics)
// grid = (128 chunks, B) = 1024 blocks x 192 thr (4 blocks/CU, 12 waves/CU)
__global__ __launch_bounds__(192) void pool1(const float* __restrict__ x,
                                             const float* __restrict__ weights,
                                             float* __restrict__ partial) {
    const int b = blockIdx.y;
    const int c = blockIdx.x;            // 128 chunks x 32 rows
    const int t = threadIdx.x;           // owns float4 at d = t*4
    const float* base = x + ((size_t)b * Ss + c * 32) * Dd;
    const float* wrow = weights + (size_t)b * Ss + c * 32;
    float4 acc = make_float4(0.f, 0.f, 0.f, 0.f);
#pragma unroll 8
    for (int i = 0; i < 32; ++i) {
        const float ww = wrow[i];
        const float4 xv = *(const float4*)(base + (size_t)i * Dd + t * 4);
        acc.x += ww * xv.x;
        acc.y += ww * xv.y;
        acc.z += ww * xv.z;
        acc.w += ww * xv.w;
    }
    *(float4*)(partial + ((size_t)(b * 128 + c)) * Dd + t * 4) = acc;
}

// ---------------- Kernel 3b: out[b][d] = sinv[b] * sum_c partial[b][c][d]
__global__ __launch_bounds__(768) void pool2(const float* __restrict__ partial,
                                             const float* __restrict__ sinv,
                                             float* __restrict__ out) {
    const int b = blockIdx.x;
    const int d = threadIdx.x;           // 0..767
    float s = 0.f;
#pragma unroll 8
    for (int c = 0; c < 128; ++c) s += partial[((size_t)(b * 128 + c)) * Dd + d];
    out[(size_t)b * Dd + d] = s * sinv[b];
}

extern "C" void kernel_launch(void* const* d_in, const int* in_sizes, int n_in,
                              void* d_out, int out_size, void* d_ws, size_t ws_size,
                              hipStream_t stream) {
    (void)in_sizes; (void)n_in; (void)ws_size; (void)out_size;
    const float* x = (const float*)d_in[0];
    const float* v = (const float*)d_in[1];
    const float* W = (const float*)d_in[2];

    char* ws = (char*)d_ws;
    __bf16* Wt = (__bf16*)ws;                             // 1,179,648 B
    float* scores2 = (float*)(ws + 1179648);              //   262,144 B (2 x 32768 f32)
    float* weights = (float*)(ws + 1179648 + 262144);     //   131,072 B
    float* sinv    = (float*)(ws + 1179648 + 262144 + 131072);  // 32 B
    float* partial = (float*)(ws + 1179648 + 262144 + 131072 + 32); // 3,145,728 B

    convW<<<dim3(Dd / 32, Dd / 32), 256, 0, stream>>>(W, Wt);
    scores_gemm<<<dim3(2 * Mm / 64), 512, 0, stream>>>(x, Wt, v, scores2);
    softmax_k<<<dim3(Bb), 256, 0, stream>>>(scores2, weights, sinv);
    pool1<<<dim3(128, Bb), 192, 0, stream>>>(x, weights, partial);
    pool2<<<dim3(Bb), 768, 0, stream>>>(partial, sinv, (float*)d_out);
}

// Round 4
// 245.722 us; speedup vs baseline: 1.3208x; 1.3208x over previous
//
#include <hip/hip_runtime.h>
#include <hip/hip_bf16.h>

// Problem: B=8, S=4096, D=768
//   y = tanh(x @ W); scores = y . v; w = softmax_S(scores); out = sum_s w * x
constexpr int Bb = 8;
constexpr int Ss = 4096;
constexpr int Dd = 768;
constexpr int Mm = Bb * Ss;      // 32768 rows

typedef __bf16 bf16x8 __attribute__((ext_vector_type(8)));
typedef float f32x4 __attribute__((ext_vector_type(4)));

__device__ __forceinline__ float fast_tanh(float x) {
    return 1.f - 2.f / (__expf(2.f * x) + 1.f);
}

__device__ __forceinline__ void load_lds16(const void* g, void* l) {
    __builtin_amdgcn_global_load_lds(
        (const __attribute__((address_space(1))) unsigned int*)g,
        (__attribute__((address_space(3))) unsigned int*)l, 16, 0, 0);
}

// ---------------- Kernel 0: W[k][n] fp32 -> Wt[n][k] bf16, with the LDS
// bank-swizzle PRE-BAKED into the global layout: within each 64B k-chunk of
// row n, 16B slot s holds original slot s ^ ((n>>1)&3). global_load_lds then
// writes LDS linearly and the GEMM reads with the same XOR -> 2-way max
// bank aliasing (free).
__global__ __launch_bounds__(256) void convW(const float* __restrict__ W,
                                             __bf16* __restrict__ Wt) {
    __shared__ float tile[32][33];
    const int tx = threadIdx.x & 31;
    const int ty = threadIdx.x >> 5;
    const int kb = blockIdx.x * 32;
    const int nb = blockIdx.y * 32;
#pragma unroll
    for (int i = 0; i < 32; i += 8)
        tile[ty + i][tx] = W[(size_t)(kb + ty + i) * Dd + nb + tx];
    __syncthreads();
#pragma unroll
    for (int i = 0; i < 32; i += 8) {
        const int n = nb + ty + i;
        const int txs = (tx & 7) | ((((tx >> 3) & 3) ^ ((n >> 1) & 3)) << 3);
        Wt[(size_t)n * Dd + kb + txs] = (__bf16)tile[tx][ty + i];
    }
}

// ---------------- Kernel 1: scores3[nb][m] = sum_n v[n]*tanh( (x@W)[m][n] )
// BM=128 x BN=256, n-split 3. 512 thr = 8 waves (2wm x 4wn), wave tile 64x64,
// 16 MFMA per K-step. FULLY-ASYNC staging: BOTH operands arrive via
// global_load_lds under counted vmcnt. A is staged as FP32 (no conversion on
// the way in; cvt fp32->bf16 happens in-register after ds_read, right before
// the MFMAs). This removes the A register round-trip / ds_write / per-step
// VMEM-latency exposure that limited rounds 0-3. A: 2-deep [128][32]f32
// (32 KB), 1-step flight. B: 3-deep [256][32]bf16 pre-swizzled Wt (48 KB),
// 2-step flight. 80 KB total -> exactly 2 blocks/CU (epilogue ssc overlays As).
// A LDS reads are conflict-free via rot-XOR 16B-slot swizzle applied on the
// gl_lds SOURCE address (linear dest + inverse-swizzled source, rule #21);
// source coalescing preserved (permutation within each 128B row segment).
// vmcnt ledger (in-order retirement): step order [A(k+1), B(k+2)]; at each
// barrier vmcnt(3) retires A(k),B(k), leaves B(k+1) flying; vmcnt(0) at k=23.
__global__ __launch_bounds__(512, 4) void scores_gemm(
    const float* __restrict__ x, const __bf16* __restrict__ Wt,
    const float* __restrict__ v, float* __restrict__ scores3) {
    __shared__ float  As[2][128 * 32];    // 2 x 16 KB (fp32 A tiles)
    __shared__ __bf16 Bs[3][256 * 32];    // 3 x 16 KB

    const int t = threadIdx.x;
    // XCD swizzle: 768 blocks, 8 XCDs -> XCD x owns ids [x*96,(x+1)*96)
    const int id = blockIdx.x;
    const int ids = ((id & 7) * 96) + (id >> 3);
    const int mb = ids / 3;               // 0..255
    const int nb = ids - mb * 3;          // 0..2
    const int lane = t & 63;
    const int wave = t >> 6;
    const int wm = wave >> 2;             // 0..1 (64-row half)
    const int wn = wave & 3;              // 0..3 (64-col slice)
    const int quad = lane >> 4;
    const int lid = lane & 15;
    const int rslot = ((quad ^ ((lid >> 1) & 3)) * 8);   // B-read swizzle

    // ---- A staging (fp32 gl_lds, swizzled source):
    // dest (linear): As[buf] f32 index j*2048 + t*4  (j=0,1)
    // row = j*64 + (t>>3); phys 16B slot p = t&7; logical = p ^ rot(row&7)
    const int sarow = t >> 3;             // 0..63  (row&7 invariant under +64)
    const int sarot = ((sarow & 1) << 2) | ((sarow >> 1) & 3);
    const int sacoll = (t & 7) ^ sarot;   // logical 16B slot -> f32 col = *4
    const float* axp = x + (size_t)(mb * 128 + sarow) * Dd + sacoll * 4;
    const float* axp1 = axp + (size_t)64 * Dd;

    // ---- B staging: 3 x 16B per thread, flat j*8192 + t*16 bytes [256 x 64B]
    const __bf16* bg[3];
    int bl[3];
#pragma unroll
    for (int j = 0; j < 3; ++j) {
        const int flat = j * 8192 / 3 * 3;    // keep it simple below
        (void)flat;
        const int f2 = j * 8192 + t * 16;     // bytes (j=0..1 used fully; j covers 24KB? no: 16KB)
        (void)f2;
        bg[j] = nullptr; bl[j] = 0;
    }
    // B tile is 256x64B = 16 KB; 512 threads x 16B = 8 KB per shot -> 2 shots.
    const __bf16* bgp[2];
    int blp[2];
#pragma unroll
    for (int j = 0; j < 2; ++j) {
        const int flat = j * 8192 + t * 16;   // bytes
        const int col = flat >> 6;
        bgp[j] = Wt + (size_t)(nb * 256 + col) * Dd + ((flat & 63) >> 1);
        blp[j] = flat >> 1;                   // bf16 index into Bs[buf]
    }

    // A-read swizzle constants (phys slot for logical 2q / 2q+1)
    const int arot = ((lid & 1) << 2) | ((lid >> 1) & 3);
    const int s0 = ((2 * quad) ^ arot) * 4;   // f32 offset of 16B slot
    const int s1 = ((2 * quad + 1) ^ arot) * 4;

    f32x4 acc[4][4];
#pragma unroll
    for (int tm = 0; tm < 4; ++tm)
#pragma unroll
        for (int nt = 0; nt < 4; ++nt) acc[tm][nt] = (f32x4){0.f, 0.f, 0.f, 0.f};

    // ---- prologue: A(0); B(0); B(1)   (order matters for the vmcnt ledger)
    load_lds16(axp, &As[0][t * 4]);
    load_lds16(axp1, &As[0][2048 + t * 4]);
#pragma unroll
    for (int j = 0; j < 2; ++j) load_lds16(bgp[j], &Bs[0][blp[j]]);
#pragma unroll
    for (int j = 0; j < 2; ++j) load_lds16(bgp[j] + 32, &Bs[1][blp[j]]);

#pragma unroll
    for (int k = 0; k < 24; ++k) {
        // Retire A(k) and everything older (incl B(k)); B(k+1) stays in flight.
        if (k == 23) asm volatile("s_waitcnt vmcnt(0)" ::: "memory");
        else         asm volatile("s_waitcnt vmcnt(2)" ::: "memory");
        __builtin_amdgcn_sched_barrier(0);
        __builtin_amdgcn_s_barrier();
        __builtin_amdgcn_sched_barrier(0);

        if (k < 23) {                     // A(k+1), 1-step flight
            load_lds16(axp + (k + 1) * 32, &As[(k + 1) & 1][t * 4]);
            load_lds16(axp1 + (k + 1) * 32, &As[(k + 1) & 1][2048 + t * 4]);
        }
        if (k < 22) {                     // B(k+2), 2-step flight
#pragma unroll
            for (int j = 0; j < 2; ++j)
                load_lds16(bgp[j] + (k + 2) * 32, &Bs[(k + 2) % 3][blp[j]]);
        }
        __builtin_amdgcn_sched_barrier(0);

        // ds_read A (fp32, swizzled) + cvt, ds_read B (bf16, swizzled)
        bf16x8 af[4], bfr[4];
#pragma unroll
        for (int tm = 0; tm < 4; ++tm) {
            const int rowb = (wm * 64 + tm * 16 + lid) * 32;
            const f32x4 lo = *(const f32x4*)(&As[k & 1][rowb + s0]);
            const f32x4 hi = *(const f32x4*)(&As[k & 1][rowb + s1]);
            bf16x8 a;
            a[0] = (__bf16)lo[0]; a[1] = (__bf16)lo[1];
            a[2] = (__bf16)lo[2]; a[3] = (__bf16)lo[3];
            a[4] = (__bf16)hi[0]; a[5] = (__bf16)hi[1];
            a[6] = (__bf16)hi[2]; a[7] = (__bf16)hi[3];
            af[tm] = a;
        }
#pragma unroll
        for (int nt = 0; nt < 4; ++nt)
            bfr[nt] = *(const bf16x8*)(&Bs[k % 3][(wn * 64 + nt * 16 + lid) * 32 + rslot]);

        __builtin_amdgcn_s_setprio(1);
#pragma unroll
        for (int tm = 0; tm < 4; ++tm)
#pragma unroll
            for (int nt = 0; nt < 4; ++nt)
                acc[tm][nt] = __builtin_amdgcn_mfma_f32_16x16x32_bf16(af[tm], bfr[nt], acc[tm][nt], 0, 0, 0);
        __builtin_amdgcn_s_setprio(0);
    }

    // ---- epilogue: fold tanh*v over this block's 256 cols, reduce to rows.
    // ssc overlays As (all A reads are done; barrier protects laggards).
    __syncthreads();
    float* ssc = (float*)&As[0][0];       // [8][64]

    float vv[4];
#pragma unroll
    for (int nt = 0; nt < 4; ++nt)
        vv[nt] = v[nb * 256 + wn * 64 + nt * 16 + lid];

#pragma unroll
    for (int tm = 0; tm < 4; ++tm)
#pragma unroll
        for (int r = 0; r < 4; ++r) {
            float s = 0.f;
#pragma unroll
            for (int nt = 0; nt < 4; ++nt) s += vv[nt] * fast_tanh(acc[tm][nt][r]);
            // C layout: col=lid, row=quad*4+r
            s += __shfl_xor(s, 1);
            s += __shfl_xor(s, 2);
            s += __shfl_xor(s, 4);
            s += __shfl_xor(s, 8);
            if (lid == 0) ssc[wave * 64 + tm * 16 + quad * 4 + r] = s;
        }
    __syncthreads();
    if (t < 128) {
        const int wmh = t >> 6;           // which 64-row half
        const int rl = t & 63;
        float s = 0.f;
#pragma unroll
        for (int ww = 0; ww < 4; ++ww) s += ssc[(wmh * 4 + ww) * 64 + rl];
        scores3[(size_t)nb * Mm + mb * 128 + t] = s;   // no atomics, no memset
    }
}

// ---------------- Kernel 2: softmax over S per batch row.
// Reads 3 n-split partials, writes UNNORMALIZED e to weights, 1/sum to sinv.
__global__ __launch_bounds__(256) void softmax_k(const float* __restrict__ scores3,
                                                 float* __restrict__ weights,
                                                 float* __restrict__ sinv) {
    const int b = blockIdx.x;
    const int t = threadIdx.x;
    const float* s0 = scores3 + (size_t)b * Ss;
    const float* s1 = s0 + Mm;
    const float* s2 = s1 + Mm;
    float* wgt = weights + (size_t)b * Ss;
    __shared__ float red[256];

    float mx = -1e30f;
    for (int i = t; i < Ss; i += 256) {
        const float sc = s0[i] + s1[i] + s2[i];
        wgt[i] = sc;                      // stash summed score
        mx = fmaxf(mx, sc);
    }
    red[t] = mx;
    __syncthreads();
    for (int o = 128; o > 0; o >>= 1) {
        if (t < o) red[t] = fmaxf(red[t], red[t + o]);
        __syncthreads();
    }
    mx = red[0];
    __syncthreads();
    float sum = 0.f;
    for (int i = t; i < Ss; i += 256) {
        const float e = __expf(wgt[i] - mx);
        wgt[i] = e;                       // unnormalized weight
        sum += e;
    }
    red[t] = sum;
    __syncthreads();
    for (int o = 128; o > 0; o >>= 1) {
        if (t < o) red[t] += red[t + o];
        __syncthreads();
    }
    if (t == 0) sinv[b] = 1.f / red[0];
}

// ---------------- Kernel 3a: per-chunk partial pool (no atomics)
// grid = (128 chunks, B) = 1024 blocks x 192 thr (4 blocks/CU, 12 waves/CU)
__global__ __launch_bounds__(192) void pool1(const float* __restrict__ x,
                                             const float* __restrict__ weights,
                                             float* __restrict__ partial) {
    const int b = blockIdx.y;
    const int c = blockIdx.x;            // 128 chunks x 32 rows
    const int t = threadIdx.x;           // owns float4 at d = t*4
    const float* base = x + ((size_t)b * Ss + c * 32) * Dd;
    const float* wrow = weights + (size_t)b * Ss + c * 32;
    float4 acc = make_float4(0.f, 0.f, 0.f, 0.f);
#pragma unroll 8
    for (int i = 0; i < 32; ++i) {
        const float ww = wrow[i];
        const float4 xv = *(const float4*)(base + (size_t)i * Dd + t * 4);
        acc.x += ww * xv.x;
        acc.y += ww * xv.y;
        acc.z += ww * xv.z;
        acc.w += ww * xv.w;
    }
    *(float4*)(partial + ((size_t)(b * 128 + c)) * Dd + t * 4) = acc;
}

// ---------------- Kernel 3b: out[b][d] = sinv[b] * sum_c partial[b][c][d]
__global__ __launch_bounds__(768) void pool2(const float* __restrict__ partial,
                                             const float* __restrict__ sinv,
                                             float* __restrict__ out) {
    const int b = blockIdx.x;
    const int d = threadIdx.x;           // 0..767
    float s = 0.f;
#pragma unroll 8
    for (int c = 0; c < 128; ++c) s += partial[((size_t)(b * 128 + c)) * Dd + d];
    out[(size_t)b * Dd + d] = s * sinv[b];
}

extern "C" void kernel_launch(void* const* d_in, const int* in_sizes, int n_in,
                              void* d_out, int out_size, void* d_ws, size_t ws_size,
                              hipStream_t stream) {
    (void)in_sizes; (void)n_in; (void)ws_size; (void)out_size;
    const float* x = (const float*)d_in[0];
    const float* v = (const float*)d_in[1];
    const float* W = (const float*)d_in[2];

    char* ws = (char*)d_ws;
    __bf16* Wt = (__bf16*)ws;                             // 1,179,648 B
    float* scores3 = (float*)(ws + 1179648);              //   393,216 B (3 x 32768 f32)
    float* weights = (float*)(ws + 1179648 + 393216);     //   131,072 B
    float* sinv    = (float*)(ws + 1179648 + 393216 + 131072);  // 32 B
    float* partial = (float*)(ws + 1179648 + 393216 + 131072 + 32); // 3,145,728 B

    convW<<<dim3(Dd / 32, Dd / 32), 256, 0, stream>>>(W, Wt);
    scores_gemm<<<dim3(3 * Mm / 128), 512, 0, stream>>>(x, Wt, v, scores3);
    softmax_k<<<dim3(Bb), 256, 0, stream>>>(scores3, weights, sinv);
    pool1<<<dim3(128, Bb), 192, 0, stream>>>(x, weights, partial);
    pool2<<<dim3(Bb), 768, 0, stream>>>(partial, sinv, (float*)d_out);
}

// Round 5
// 241.984 us; speedup vs baseline: 1.3412x; 1.0154x over previous
//
#include <hip/hip_runtime.h>
#include <hip/hip_bf16.h>

// Problem: B=8, S=4096, D=768
//   y = tanh(x @ W); scores = y . v; w = softmax_S(scores); out = sum_s w * x
constexpr int Bb = 8;
constexpr int Ss = 4096;
constexpr int Dd = 768;
constexpr int Mm = Bb * Ss;      // 32768 rows

typedef __bf16 bf16x8 __attribute__((ext_vector_type(8)));
typedef float f32x4 __attribute__((ext_vector_type(4)));

__device__ __forceinline__ float fast_tanh(float x) {
    return 1.f - 2.f / (__expf(2.f * x) + 1.f);
}

__device__ __forceinline__ void load_lds16(const void* g, void* l) {
    __builtin_amdgcn_global_load_lds(
        (const __attribute__((address_space(1))) unsigned int*)g,
        (__attribute__((address_space(3))) unsigned int*)l, 16, 0, 0);
}

// ---------------- Kernel 0a: W[k][n] fp32 -> Wt[n][k] bf16, with the LDS
// bank-swizzle PRE-BAKED into the global layout (16B slot s -> s ^ ((n>>1)&3)
// within each 64B k-chunk). Proven: 0 bank conflicts on the B reads.
__global__ __launch_bounds__(256) void convW(const float* __restrict__ W,
                                             __bf16* __restrict__ Wt) {
    __shared__ float tile[32][33];
    const int tx = threadIdx.x & 31;
    const int ty = threadIdx.x >> 5;
    const int kb = blockIdx.x * 32;
    const int nb = blockIdx.y * 32;
#pragma unroll
    for (int i = 0; i < 32; i += 8)
        tile[ty + i][tx] = W[(size_t)(kb + ty + i) * Dd + nb + tx];
    __syncthreads();
#pragma unroll
    for (int i = 0; i < 32; i += 8) {
        const int n = nb + ty + i;
        const int txs = (tx & 7) | ((((tx >> 3) & 3) ^ ((n >> 1) & 3)) << 3);
        Wt[(size_t)n * Dd + kb + txs] = (__bf16)tile[tx][ty + i];
    }
}

// ---------------- Kernel 0b: x fp32 -> xb bf16 (layout-preserving, streaming).
// Unlocks the m97-shape gemm: A arrives via global_load_lds like B, removing
// the fp32->bf16 cvt + ds_write + load-wait from the K-loop critical path.
__global__ __launch_bounds__(512) void convX(const float* __restrict__ x,
                                             __bf16* __restrict__ xb) {
    const size_t i = ((size_t)blockIdx.x * 512 + threadIdx.x) * 8;
    const float4 a = *(const float4*)(x + i);
    const float4 b = *(const float4*)(x + i + 4);
    bf16x8 p;
    p[0] = (__bf16)a.x; p[1] = (__bf16)a.y; p[2] = (__bf16)a.z; p[3] = (__bf16)a.w;
    p[4] = (__bf16)b.x; p[5] = (__bf16)b.y; p[6] = (__bf16)b.z; p[7] = (__bf16)b.w;
    *(bf16x8*)(xb + i) = p;
}

// ---------------- Kernel 1 (fast path): scores3[nb][m] = sum_n v[n]*tanh((xW)[m][n])
// BM=128 x BN=256, n-split 3, 512 thr = 8 waves (2wm x 4wn), wave tile 64x64.
// m97 structure: BOTH operands via global_load_lds bf16, 3-deep LDS, counted
// vmcnt (3 in loop, 0 only at the last step), one barrier per K-step, setprio
// around the 16-MFMA cluster. Per step: 3 gl_lds + 8 ds_read_b128 + 16 MFMA —
// no cvt, no ds_write, no A-regs (reg pressure freed vs round-2 champion).
// A-read (quad*8 slot) is uniform 8 lanes/bank-quad = conflict-free; B keeps
// the Wt-baked swizzle. LDS 74KB -> 2 blocks/CU. XCD-bijective swizzle.
__global__ __launch_bounds__(512, 4) void scores_gemm(
    const __bf16* __restrict__ xb, const __bf16* __restrict__ Wt,
    const float* __restrict__ v, float* __restrict__ scores3) {
    __shared__ __bf16 As[3][128 * 32];    // 3 x 8 KB
    __shared__ __bf16 Bs[3][256 * 32];    // 3 x 16 KB
    __shared__ float ssc[8][64];          // 2 KB

    const int t = threadIdx.x;
    // XCD swizzle: 768 blocks, 8 XCDs -> XCD x owns ids [x*96,(x+1)*96)
    const int id = blockIdx.x;
    const int ids = ((id & 7) * 96) + (id >> 3);
    const int mb = ids / 3;               // 0..255
    const int nb = ids - mb * 3;          // 0..2
    const int lane = t & 63;
    const int wave = t >> 6;
    const int wm = wave >> 2;             // 0..1 (64-row half)
    const int wn = wave & 3;              // 0..3 (64-col slice)
    const int quad = lane >> 4;
    const int lid = lane & 15;
    const int rslot = ((quad ^ ((lid >> 1) & 3)) * 8);   // B-read swizzle

    // A staging: 1 shot of 512x16B over the [128 x 64B] tile.
    // thread t -> row t>>2, 16B slot t&3; LDS dest linear t*16B.
    const __bf16* axg = xb + (size_t)(mb * 128 + (t >> 2)) * Dd + (t & 3) * 8;
    const int awl = t * 8;                // bf16 index into As[buf]

    // B staging: 2 shots of 512x16B over the [256 x 64B] tile.
    const __bf16* bgp[2];
    int blp[2];
#pragma unroll
    for (int j = 0; j < 2; ++j) {
        const int flat = j * 8192 + t * 16;   // bytes
        const int col = flat >> 6;
        bgp[j] = Wt + (size_t)(nb * 256 + col) * Dd + ((flat & 63) >> 1);
        blp[j] = flat >> 1;                   // bf16 index into Bs[buf]
    }

    f32x4 acc[4][4];
#pragma unroll
    for (int tm = 0; tm < 4; ++tm)
#pragma unroll
        for (int nt = 0; nt < 4; ++nt) acc[tm][nt] = (f32x4){0.f, 0.f, 0.f, 0.f};

    // ---- prologue: S(0)=[A0,B0,B0]; S(1)=[A1,B1,B1]  (6 ops in flight)
    load_lds16(axg, &As[0][awl]);
#pragma unroll
    for (int j = 0; j < 2; ++j) load_lds16(bgp[j], &Bs[0][blp[j]]);
    load_lds16(axg + 32, &As[1][awl]);
#pragma unroll
    for (int j = 0; j < 2; ++j) load_lds16(bgp[j] + 32, &Bs[1][blp[j]]);

#pragma unroll
    for (int k = 0; k < 24; ++k) {
        // Ledger (in-order retire): outstanding = S(k)[3] + S(k+1)[3];
        // need S(k) retired, S(k+1) keeps flying -> vmcnt(3). k=23: drain.
        if (k == 23) asm volatile("s_waitcnt vmcnt(0)" ::: "memory");
        else         asm volatile("s_waitcnt vmcnt(3)" ::: "memory");
        __builtin_amdgcn_sched_barrier(0);
        __builtin_amdgcn_s_barrier();     // publish buf k
        __builtin_amdgcn_sched_barrier(0);

        if (k < 22) {                     // S(k+2), 2-step flight
            load_lds16(axg + (k + 2) * 32, &As[(k + 2) % 3][awl]);
#pragma unroll
            for (int j = 0; j < 2; ++j)
                load_lds16(bgp[j] + (k + 2) * 32, &Bs[(k + 2) % 3][blp[j]]);
        }
        __builtin_amdgcn_sched_barrier(0);

        bf16x8 af[4], bfr[4];
#pragma unroll
        for (int tm = 0; tm < 4; ++tm)
            af[tm] = *(const bf16x8*)(&As[k % 3][(wm * 64 + tm * 16 + lid) * 32 + quad * 8]);
#pragma unroll
        for (int nt = 0; nt < 4; ++nt)
            bfr[nt] = *(const bf16x8*)(&Bs[k % 3][(wn * 64 + nt * 16 + lid) * 32 + rslot]);

        __builtin_amdgcn_s_setprio(1);
#pragma unroll
        for (int tm = 0; tm < 4; ++tm)
#pragma unroll
            for (int nt = 0; nt < 4; ++nt)
                acc[tm][nt] = __builtin_amdgcn_mfma_f32_16x16x32_bf16(af[tm], bfr[nt], acc[tm][nt], 0, 0, 0);
        __builtin_amdgcn_s_setprio(0);
    }

    // ---- epilogue: fold tanh*v over this block's 256 cols, reduce to rows
    float vv[4];
#pragma unroll
    for (int nt = 0; nt < 4; ++nt)
        vv[nt] = v[nb * 256 + wn * 64 + nt * 16 + lid];

#pragma unroll
    for (int tm = 0; tm < 4; ++tm)
#pragma unroll
        for (int r = 0; r < 4; ++r) {
            float s = 0.f;
#pragma unroll
            for (int nt = 0; nt < 4; ++nt) s += vv[nt] * fast_tanh(acc[tm][nt][r]);
            // C layout: col=lid, row=quad*4+r
            s += __shfl_xor(s, 1);
            s += __shfl_xor(s, 2);
            s += __shfl_xor(s, 4);
            s += __shfl_xor(s, 8);
            if (lid == 0) ssc[wave][tm * 16 + quad * 4 + r] = s;
        }
    __syncthreads();
    if (t < 128) {
        const int wmh = t >> 6;           // which 64-row half
        const int rl = t & 63;
        float s = 0.f;
#pragma unroll
        for (int ww = 0; ww < 4; ++ww) s += ssc[wmh * 4 + ww][rl];
        scores3[(size_t)nb * Mm + mb * 128 + t] = s;   // no atomics, no memset
    }
}

// ---------------- Kernel 1 (fallback, ws too small for xb): round-2 champion
// verbatim — A reg-staged from fp32 x, 3-deep B, counted vmcnt(2), setprio.
__global__ __launch_bounds__(512, 4) void scores_gemm_fb(
    const float* __restrict__ x, const __bf16* __restrict__ Wt,
    const float* __restrict__ v, float* __restrict__ scores3) {
    __shared__ __bf16 As[3][128 * 32];
    __shared__ __bf16 Bs[3][256 * 32];
    __shared__ float ssc[8][64];

    const int t = threadIdx.x;
    const int id = blockIdx.x;
    const int ids = ((id & 7) * 96) + (id >> 3);
    const int mb = ids / 3;
    const int nb = ids - mb * 3;
    const int lane = t & 63;
    const int wave = t >> 6;
    const int wm = wave >> 2;
    const int wn = wave & 3;
    const int quad = lane >> 4;
    const int lid = lane & 15;
    const int rslot = ((quad ^ ((lid >> 1) & 3)) * 8);

    const int arow = t >> 2;
    const int aslotraw = t & 3;
    const int aslot = aslotraw ^ ((arow >> 1) & 3);
    const float* agp = x + (size_t)(mb * 128 + arow) * Dd + aslotraw * 8;
    const int awr = arow * 32 + aslot * 8;

    const __bf16* bgp[2];
    int blp[2];
#pragma unroll
    for (int j = 0; j < 2; ++j) {
        const int flat = j * 8192 + t * 16;
        const int col = flat >> 6;
        bgp[j] = Wt + (size_t)(nb * 256 + col) * Dd + ((flat & 63) >> 1);
        blp[j] = flat >> 1;
    }

    f32x4 acc[4][4];
#pragma unroll
    for (int tm = 0; tm < 4; ++tm)
#pragma unroll
        for (int nt = 0; nt < 4; ++nt) acc[tm][nt] = (f32x4){0.f, 0.f, 0.f, 0.f};

    {
        const float4 a0 = *(const float4*)(agp);
        const float4 a1 = *(const float4*)(agp + 4);
        bf16x8 pa;
        pa[0] = (__bf16)a0.x; pa[1] = (__bf16)a0.y; pa[2] = (__bf16)a0.z; pa[3] = (__bf16)a0.w;
        pa[4] = (__bf16)a1.x; pa[5] = (__bf16)a1.y; pa[6] = (__bf16)a1.z; pa[7] = (__bf16)a1.w;
        *(bf16x8*)(&As[0][awr]) = pa;
#pragma unroll
        for (int j = 0; j < 2; ++j) load_lds16(bgp[j], &Bs[0][blp[j]]);
    }

#pragma unroll
    for (int k = 0; k < 24; ++k) {
        if (k == 23) asm volatile("s_waitcnt vmcnt(0) lgkmcnt(0)" ::: "memory");
        else         asm volatile("s_waitcnt vmcnt(2) lgkmcnt(0)" ::: "memory");
        __builtin_amdgcn_sched_barrier(0);
        __builtin_amdgcn_s_barrier();
        __builtin_amdgcn_sched_barrier(0);

        float4 a0n, a1n;
        if (k < 23) {
            a0n = *(const float4*)(agp + (k + 1) * 32);
            a1n = *(const float4*)(agp + (k + 1) * 32 + 4);
        }
        __builtin_amdgcn_sched_barrier(0);
        if (k < 22) {
#pragma unroll
            for (int j = 0; j < 2; ++j)
                load_lds16(bgp[j] + (k + 2) * 32, &Bs[(k + 2) % 3][blp[j]]);
        }

        bf16x8 af[4], bfr[4];
#pragma unroll
        for (int tm = 0; tm < 4; ++tm)
            af[tm] = *(const bf16x8*)(&As[k % 3][(wm * 64 + tm * 16 + lid) * 32 + quad * 8]);
#pragma unroll
        for (int nt = 0; nt < 4; ++nt)
            bfr[nt] = *(const bf16x8*)(&Bs[k % 3][(wn * 64 + nt * 16 + lid) * 32 + rslot]);

        __builtin_amdgcn_s_setprio(1);
#pragma unroll
        for (int tm = 0; tm < 4; ++tm)
#pragma unroll
            for (int nt = 0; nt < 4; ++nt)
                acc[tm][nt] = __builtin_amdgcn_mfma_f32_16x16x32_bf16(af[tm], bfr[nt], acc[tm][nt], 0, 0, 0);
        __builtin_amdgcn_s_setprio(0);

        if (k < 23) {
            bf16x8 pa;
            pa[0] = (__bf16)a0n.x; pa[1] = (__bf16)a0n.y; pa[2] = (__bf16)a0n.z; pa[3] = (__bf16)a0n.w;
            pa[4] = (__bf16)a1n.x; pa[5] = (__bf16)a1n.y; pa[6] = (__bf16)a1n.z; pa[7] = (__bf16)a1n.w;
            *(bf16x8*)(&As[(k + 1) % 3][awr]) = pa;
        }
    }

    float vv[4];
#pragma unroll
    for (int nt = 0; nt < 4; ++nt)
        vv[nt] = v[nb * 256 + wn * 64 + nt * 16 + lid];

#pragma unroll
    for (int tm = 0; tm < 4; ++tm)
#pragma unroll
        for (int r = 0; r < 4; ++r) {
            float s = 0.f;
#pragma unroll
            for (int nt = 0; nt < 4; ++nt) s += vv[nt] * fast_tanh(acc[tm][nt][r]);
            s += __shfl_xor(s, 1);
            s += __shfl_xor(s, 2);
            s += __shfl_xor(s, 4);
            s += __shfl_xor(s, 8);
            if (lid == 0) ssc[wave][tm * 16 + quad * 4 + r] = s;
        }
    __syncthreads();
    if (t < 128) {
        const int wmh = t >> 6;
        const int rl = t & 63;
        float s = 0.f;
#pragma unroll
        for (int ww = 0; ww < 4; ++ww) s += ssc[wmh * 4 + ww][rl];
        scores3[(size_t)nb * Mm + mb * 128 + t] = s;
    }
}

// ---------------- Kernel 2: softmax over S per batch row.
// Reads 3 n-split partials, writes UNNORMALIZED e to weights, 1/sum to sinv.
__global__ __launch_bounds__(256) void softmax_k(const float* __restrict__ scores3,
                                                 float* __restrict__ weights,
                                                 float* __restrict__ sinv) {
    const int b = blockIdx.x;
    const int t = threadIdx.x;
    const float* s0 = scores3 + (size_t)b * Ss;
    const float* s1 = s0 + Mm;
    const float* s2 = s1 + Mm;
    float* wgt = weights + (size_t)b * Ss;
    __shared__ float red[256];

    float mx = -1e30f;
    for (int i = t; i < Ss; i += 256) {
        const float sc = s0[i] + s1[i] + s2[i];
        wgt[i] = sc;
        mx = fmaxf(mx, sc);
    }
    red[t] = mx;
    __syncthreads();
    for (int o = 128; o > 0; o >>= 1) {
        if (t < o) red[t] = fmaxf(red[t], red[t + o]);
        __syncthreads();
    }
    mx = red[0];
    __syncthreads();
    float sum = 0.f;
    for (int i = t; i < Ss; i += 256) {
        const float e = __expf(wgt[i] - mx);
        wgt[i] = e;
        sum += e;
    }
    red[t] = sum;
    __syncthreads();
    for (int o = 128; o > 0; o >>= 1) {
        if (t < o) red[t] += red[t + o];
        __syncthreads();
    }
    if (t == 0) sinv[b] = 1.f / red[0];
}

// ---------------- Kernel 3a: per-chunk partial pool (no atomics)
__global__ __launch_bounds__(192) void pool1(const float* __restrict__ x,
                                             const float* __restrict__ weights,
                                             float* __restrict__ partial) {
    const int b = blockIdx.y;
    const int c = blockIdx.x;            // 128 chunks x 32 rows
    const int t = threadIdx.x;           // owns float4 at d = t*4
    const float* base = x + ((size_t)b * Ss + c * 32) * Dd;
    const float* wrow = weights + (size_t)b * Ss + c * 32;
    float4 acc = make_float4(0.f, 0.f, 0.f, 0.f);
#pragma unroll 8
    for (int i = 0; i < 32; ++i) {
        const float ww = wrow[i];
        const float4 xv = *(const float4*)(base + (size_t)i * Dd + t * 4);
        acc.x += ww * xv.x;
        acc.y += ww * xv.y;
        acc.z += ww * xv.z;
        acc.w += ww * xv.w;
    }
    *(float4*)(partial + ((size_t)(b * 128 + c)) * Dd + t * 4) = acc;
}

// ---------------- Kernel 3b: out[b][d] = sinv[b] * sum_c partial[b][c][d]
__global__ __launch_bounds__(768) void pool2(const float* __restrict__ partial,
                                             const float* __restrict__ sinv,
                                             float* __restrict__ out) {
    const int b = blockIdx.x;
    const int d = threadIdx.x;           // 0..767
    float s = 0.f;
#pragma unroll 8
    for (int c = 0; c < 128; ++c) s += partial[((size_t)(b * 128 + c)) * Dd + d];
    out[(size_t)b * Dd + d] = s * sinv[b];
}

extern "C" void kernel_launch(void* const* d_in, const int* in_sizes, int n_in,
                              void* d_out, int out_size, void* d_ws, size_t ws_size,
                              hipStream_t stream) {
    (void)in_sizes; (void)n_in; (void)out_size;
    const float* x = (const float*)d_in[0];
    const float* v = (const float*)d_in[1];
    const float* W = (const float*)d_in[2];

    char* ws = (char*)d_ws;
    // layout: Wt | scores3 | weights | sinv | partial | xb
    constexpr size_t OFF_WT   = 0;
    constexpr size_t OFF_SC   = 1179648;
    constexpr size_t OFF_WG   = OFF_SC + 393216;
    constexpr size_t OFF_SI   = OFF_WG + 131072;
    constexpr size_t OFF_PA   = OFF_SI + 128;
    constexpr size_t OFF_XB   = OFF_PA + 3145728;
    constexpr size_t NEED     = OFF_XB + (size_t)Mm * Dd * 2;   // ~55.2 MB

    __bf16* Wt      = (__bf16*)(ws + OFF_WT);
    float* scores3  = (float*)(ws + OFF_SC);
    float* weights  = (float*)(ws + OFF_WG);
    float* sinv     = (float*)(ws + OFF_SI);
    float* partial  = (float*)(ws + OFF_PA);
    __bf16* xb      = (__bf16*)(ws + OFF_XB);

    convW<<<dim3(Dd / 32, Dd / 32), 256, 0, stream>>>(W, Wt);
    if (ws_size >= NEED) {
        convX<<<dim3((Mm * Dd) / (512 * 8)), 512, 0, stream>>>(x, xb);
        scores_gemm<<<dim3(3 * Mm / 128), 512, 0, stream>>>(xb, Wt, v, scores3);
    } else {
        scores_gemm_fb<<<dim3(3 * Mm / 128), 512, 0, stream>>>(x, Wt, v, scores3);
    }
    softmax_k<<<dim3(Bb), 256, 0, stream>>>(scores3, weights, sinv);
    pool1<<<dim3(128, Bb), 192, 0, stream>>>(x, weights, partial);
    pool2<<<dim3(Bb), 768, 0, stream>>>(partial, sinv, (float*)d_out);
}